// Round 16
// baseline (938.152 us; speedup 1.0000x reference)
//
#include <hip/hip_runtime.h>

namespace {

constexpr int BATCH = 4096;
constexpr int DIN   = 2048;
constexpr int HID   = 1024;
constexpr int NEMB  = 1024;
constexpr int EDIM  = 8;
constexpr float LN_EPS = 1e-5f;
constexpr float BETA   = 0.001f;

typedef __attribute__((ext_vector_type(8))) short bf16x8;
typedef __attribute__((ext_vector_type(4))) float f32x4;

__device__ inline unsigned short f2bf(float f) {
  unsigned int x = __float_as_uint(f);
  x += 0x7FFFu + ((x >> 16) & 1u);      // RNE
  return (unsigned short)(x >> 16);
}
__device__ inline void gl16(const void* g, void* l) {
  __builtin_amdgcn_global_load_lds(
      (const __attribute__((address_space(1))) unsigned int*)g,
      (__attribute__((address_space(3))) unsigned int*)l, 16, 0, 0);
}

// ---------------- GEMM fp32 split-K=2 (encoder) — BK=16 + LDS dbuf --------
// Math BIT-IDENTICAL to the R7/R12-proven version (same BK-16 partial-acc
// chains, same FMA order). Schedule-only change vs R12: double-buffered LDS
// with ONE barrier per tile — SWRITE(next) overlaps other waves' compute,
// and the gload vmcnt wait lands after compute instead of between barriers.
// R15's BK=32 spilled (WRITE_SIZE 415MB); this keeps R12's live-state shape.
__global__ __launch_bounds__(256) void gemm_f32_sk(
    const float* __restrict__ A, const float* __restrict__ B,
    float* __restrict__ P, int M, int N, int K)
{
  constexpr int BM = 128, BN = 128, BK = 16;
  __shared__ float As[2][BK][BM + 4];    // 2 x 8448 B
  __shared__ float Bsf[2][16 * 132];     // 2 x 8448 B, j-stride 132
  const int t  = threadIdx.x;
  const int tx = t & 15, ty = t >> 4;
  const int bm = blockIdx.y * BM, bn = blockIdx.x * BN;
  const int Kh = K >> 1, kbeg = blockIdx.z * Kh;
  const int NT = Kh / BK;
  float* Pz = P + (size_t)blockIdx.z * M * N;

  const int a_m = t >> 1, a_k = (t & 1) << 3;
  const int b_k = t >> 4;

  const float* Ap = A + (size_t)(bm + a_m) * K + kbeg + a_k;
  const float* Bp = B + (size_t)(kbeg + b_k) * N + (bn + tx * 8);

  float4 av0, av1, bv0, bv1;
  auto GLOAD = [&](int tk) {
    const int k0 = tk * BK;
    av0 = *(const float4*)(Ap + k0);
    av1 = *(const float4*)(Ap + k0 + 4);
    bv0 = *(const float4*)(Bp + (size_t)k0 * N);
    bv1 = *(const float4*)(Bp + (size_t)k0 * N + 4);
  };
  auto SWRITE = [&](int buf) {
    As[buf][a_k + 0][a_m] = av0.x;
    As[buf][a_k + 1][a_m] = av0.y;
    As[buf][a_k + 2][a_m] = av0.z;
    As[buf][a_k + 3][a_m] = av0.w;
    As[buf][a_k + 4][a_m] = av1.x;
    As[buf][a_k + 5][a_m] = av1.y;
    As[buf][a_k + 6][a_m] = av1.z;
    As[buf][a_k + 7][a_m] = av1.w;
    float* Bq = &Bsf[buf][tx * 132 + b_k * 8];
    *(float4*)(Bq)     = bv0;
    *(float4*)(Bq + 4) = bv1;
  };

  float acc[8][8] = {};

  GLOAD(0);
  SWRITE(0);
  for (int tk = 0; tk < NT; ++tk) {
    __syncthreads();                 // buf[tk&1] visible; prior reads done
    const int cur = tk & 1;
    if (tk + 1 < NT) GLOAD(tk + 1);  // issue next loads (regs)

    float part[8][8] = {};
#pragma unroll
    for (int k = 0; k < BK; ++k) {
      float a[8], b[8];
      *(float4*)(a)     = *(const float4*)&As[cur][k][ty * 8];
      *(float4*)(a + 4) = *(const float4*)&As[cur][k][ty * 8 + 4];
      *(float4*)(b)     = *(const float4*)&Bsf[cur][tx * 132 + k * 8];
      *(float4*)(b + 4) = *(const float4*)&Bsf[cur][tx * 132 + k * 8 + 4];
#pragma unroll
      for (int i = 0; i < 8; ++i)
#pragma unroll
        for (int j = 0; j < 8; ++j)
          part[i][j] = fmaf(a[i], b[j], part[i][j]);
    }
#pragma unroll
    for (int i = 0; i < 8; ++i)
#pragma unroll
      for (int j = 0; j < 8; ++j)
        acc[i][j] += part[i][j];

    if (tk + 1 < NT) SWRITE((tk + 1) & 1);  // overlaps other waves' compute
  }

#pragma unroll
  for (int i = 0; i < 8; ++i) {
    float* Pr = Pz + (size_t)(bm + ty * 8 + i) * N + bn + tx * 8;
    *(float4*)(Pr)     = *(float4*)&acc[i][0];
    *(float4*)(Pr + 4) = *(float4*)&acc[i][4];
  }
}

// ---------------- fused reduce + bias + LayerNorm (+ReLU), f32 out --------
template<bool RELU>
__global__ __launch_bounds__(256) void ln_sk(
    const float* __restrict__ P0, const float* __restrict__ P1,
    const float* __restrict__ bias, float* __restrict__ Y,
    const float* __restrict__ g, const float* __restrict__ be)
{
  const int t = threadIdx.x;
  const size_t base = (size_t)blockIdx.x * HID + t * 4;
  float4 p0 = *(const float4*)(P0 + base);
  float4 p1 = *(const float4*)(P1 + base);
  float4 bb = *(const float4*)(bias + t * 4);
  float4 v;
  v.x = (p0.x + p1.x) + bb.x;
  v.y = (p0.y + p1.y) + bb.y;
  v.z = (p0.z + p1.z) + bb.z;
  v.w = (p0.w + p1.w) + bb.w;
  float s = v.x + v.y + v.z + v.w;
  float q = v.x * v.x + v.y * v.y + v.z * v.z + v.w * v.w;
#pragma unroll
  for (int off = 32; off > 0; off >>= 1) {
    s += __shfl_down(s, off);
    q += __shfl_down(q, off);
  }
  __shared__ float ls[4], lq[4];
  if ((t & 63) == 0) { ls[t >> 6] = s; lq[t >> 6] = q; }
  __syncthreads();
  s = ls[0] + ls[1] + ls[2] + ls[3];
  q = lq[0] + lq[1] + lq[2] + lq[3];
  const float mean = s * (1.0f / HID);
  const float var  = q * (1.0f / HID) - mean * mean;
  const float rstd = rsqrtf(var + LN_EPS);
  float4 gv = *(const float4*)(g + t * 4);
  float4 bv = *(const float4*)(be + t * 4);
  float4 o;
  o.x = (v.x - mean) * rstd * gv.x + bv.x;
  o.y = (v.y - mean) * rstd * gv.y + bv.y;
  o.z = (v.z - mean) * rstd * gv.z + bv.z;
  o.w = (v.w - mean) * rstd * gv.w + bv.w;
  if (RELU) {
    o.x = fmaxf(o.x, 0.0f); o.y = fmaxf(o.y, 0.0f);
    o.z = fmaxf(o.z, 0.0f); o.w = fmaxf(o.w, 0.0f);
  }
  *(float4*)(Y + base) = o;
}

// ---------------- GEMM bf16 MFMA (decoder) — R6-proven --------------------
__global__ __launch_bounds__(256) void gemm_mfma(
    const unsigned short* __restrict__ Ah, const unsigned short* __restrict__ Bh,
    const float* __restrict__ bias, float* __restrict__ C,
    int M, int N, int K)
{
  constexpr int BM = 128, BN = 64, BK = 64;
  __shared__ unsigned short lds[(BM + BN) * BK];        // 24 KB
  const int t = threadIdx.x, l = t & 63, w = t >> 6;
  const int wr = w >> 1, wc = w & 1;
  const int m0 = blockIdx.y * BM, n0 = blockIdx.x * BN;
  const int NT = K / BK;

  const int AHo = 0, BHo = BM * BK * 2;

  const int srow = t >> 3, scol = t & 7;
  size_t aoff[4]; int adst[4];
#pragma unroll
  for (int i = 0; i < 4; ++i) {
    int r = srow + 32 * i;
    aoff[i] = (size_t)(m0 + r) * K + ((scol ^ (r & 7)) << 3);
    adst[i] = r * 128 + scol * 16;
  }
  size_t boff[2]; int bdst[2];
#pragma unroll
  for (int i = 0; i < 2; ++i) {
    int r = srow + 32 * i;
    boff[i] = (size_t)(n0 + r) * K + ((scol ^ (r & 7)) << 3);
    bdst[i] = r * 128 + scol * 16;
  }
  char* lc = (char*)lds;

  auto GLOAD = [&](int tk) {
    const size_t k0 = (size_t)tk * BK;
#pragma unroll
    for (int i = 0; i < 4; ++i) gl16(Ah + aoff[i] + k0, lc + AHo + adst[i]);
#pragma unroll
    for (int i = 0; i < 2; ++i) gl16(Bh + boff[i] + k0, lc + BHo + bdst[i]);
  };

  f32x4 acc[4][2];
#pragma unroll
  for (int i = 0; i < 4; ++i)
#pragma unroll
    for (int j = 0; j < 2; ++j) acc[i][j] = 0.0f;

  const int l15 = l & 15, kb0 = l >> 4;
  const int swz = (l15 & 7) << 4;
  int arow[4], brow[2];
#pragma unroll
  for (int fm = 0; fm < 4; ++fm) arow[fm] = (wr * 64 + fm * 16 + l15) * 128;
#pragma unroll
  for (int fn = 0; fn < 2; ++fn) brow[fn] = (wc * 32 + fn * 16 + l15) * 128;

  GLOAD(0);
  for (int tk = 0; tk < NT; ++tk) {
    __syncthreads();
    const char* p = (const char*)lds;
#pragma unroll
    for (int kh = 0; kh < 2; ++kh) {
      const int kby = (kh * 64 + kb0 * 16) ^ swz;
      bf16x8 af[4], bf2[2];
#pragma unroll
      for (int fm = 0; fm < 4; ++fm)
        af[fm] = *(const bf16x8*)(p + AHo + arow[fm] + kby);
#pragma unroll
      for (int fn = 0; fn < 2; ++fn)
        bf2[fn] = *(const bf16x8*)(p + BHo + brow[fn] + kby);
#pragma unroll
      for (int fm = 0; fm < 4; ++fm)
#pragma unroll
        for (int fn = 0; fn < 2; ++fn)
          acc[fm][fn] = __builtin_amdgcn_mfma_f32_16x16x32_bf16(
              af[fm], bf2[fn], acc[fm][fn], 0, 0, 0);
    }
    __syncthreads();
    if (tk + 1 < NT) GLOAD(tk + 1);
  }

  const int rb = (l >> 4) * 4;
#pragma unroll
  for (int fn = 0; fn < 2; ++fn) {
    const int n = n0 + wc * 32 + fn * 16 + l15;
    const float bv = bias[n];
#pragma unroll
    for (int fm = 0; fm < 4; ++fm) {
      const int m = m0 + wr * 64 + fm * 16 + rb;
      float* Cp = C + (size_t)m * N + n;
#pragma unroll
      for (int ri = 0; ri < 4; ++ri)
        Cp[(size_t)ri * N] = acc[fm][fn][ri] + bv;
    }
  }
}

// ---------------- weight convert + transpose: Wt[N][K] bf16 ---------------
__global__ __launch_bounds__(256) void conv_w_t(
    const float* __restrict__ W, unsigned short* __restrict__ Wt, int K, int N)
{
  __shared__ float tile[32][33];
  const int tx = threadIdx.x & 31, ty = threadIdx.x >> 5;
  const int n0 = blockIdx.x * 32, k0 = blockIdx.y * 32;
#pragma unroll
  for (int r = ty; r < 32; r += 8)
    tile[r][tx] = W[(size_t)(k0 + r) * N + n0 + tx];
  __syncthreads();
#pragma unroll
  for (int r = ty; r < 32; r += 8)
    Wt[(size_t)(n0 + r) * K + k0 + tx] = f2bf(tile[tx][r]);
}

// ---------------- LayerNorm (+ReLU), f32 in, bf16 out (decoder) -----------
template<bool RELU>
__global__ __launch_bounds__(256) void ln_act(
    const float* __restrict__ X, unsigned short* __restrict__ Y,
    const float* __restrict__ g, const float* __restrict__ be)
{
  const int t = threadIdx.x;
  const size_t base = (size_t)blockIdx.x * HID + t * 4;
  float4 v = *(const float4*)(X + base);
  float s = v.x + v.y + v.z + v.w;
  float q = v.x * v.x + v.y * v.y + v.z * v.z + v.w * v.w;
#pragma unroll
  for (int off = 32; off > 0; off >>= 1) {
    s += __shfl_down(s, off);
    q += __shfl_down(q, off);
  }
  __shared__ float ls[4], lq[4];
  if ((t & 63) == 0) { ls[t >> 6] = s; lq[t >> 6] = q; }
  __syncthreads();
  s = ls[0] + ls[1] + ls[2] + ls[3];
  q = lq[0] + lq[1] + lq[2] + lq[3];
  const float mean = s * (1.0f / HID);
  const float var  = q * (1.0f / HID) - mean * mean;
  const float rstd = rsqrtf(var + LN_EPS);
  float4 gv = *(const float4*)(g + t * 4);
  float4 bv = *(const float4*)(be + t * 4);
  float4 o;
  o.x = (v.x - mean) * rstd * gv.x + bv.x;
  o.y = (v.y - mean) * rstd * gv.y + bv.y;
  o.z = (v.z - mean) * rstd * gv.z + bv.z;
  o.w = (v.w - mean) * rstd * gv.w + bv.w;
  if (RELU) {
    o.x = fmaxf(o.x, 0.0f); o.y = fmaxf(o.y, 0.0f);
    o.z = fmaxf(o.z, 0.0f); o.w = fmaxf(o.w, 0.0f);
  }
  ushort4 u = { f2bf(o.x), f2bf(o.y), f2bf(o.z), f2bf(o.w) };
  *(ushort4*)(Y + base) = u;
}

// ---------------- qn precompute: qn[i] = 0.5*|e_i|^2 ----------------------
__global__ __launch_bounds__(256) void prep_qn(
    const float* __restrict__ CB, float* __restrict__ QN)
{
  const int i = blockIdx.x * 256 + threadIdx.x;
  const float* e = CB + (size_t)i * EDIM;
  float s = 0.0f;
#pragma unroll
  for (int j = 0; j < EDIM; ++j) s += e[j] * e[j];
  QN[i] = 0.5f * s;
}

// ---------------- VQ v8: SGPR-fed + med3 tracking + wave-uniform skip -----
__global__ __launch_bounds__(256) void vq_kernel(
    const float* __restrict__ Z, const float* __restrict__ CB,
    const float* __restrict__ QN,
    unsigned short* __restrict__ ZQb, float* __restrict__ partial)
{
  const int t = threadIdx.x;
  const size_t sv = (size_t)blockIdx.x * 256 + t;
  float z[EDIM];
  *(float4*)(z)     = *(const float4*)(Z + sv * EDIM);
  *(float4*)(z + 4) = *(const float4*)(Z + sv * EDIM + 4);

  float b1 = 1e30f, b2 = 1e30f;
  int   i1 = 0, i2 = 0;

  for (int i = 0; i < NEMB; i += 4) {
    const float4 qv = *(const float4*)(QN + i);          // uniform -> s_load
#pragma unroll
    for (int u = 0; u < 4; ++u) {
      const float4 e0 = *(const float4*)(CB + (size_t)(i + u) * EDIM);
      const float4 e1 = *(const float4*)(CB + (size_t)(i + u) * EDIM + 4);
      const float q = (u == 0) ? qv.x : (u == 1) ? qv.y : (u == 2) ? qv.z : qv.w;
      const int ii = i + u;
      float d = q;
      d = fmaf(-z[0], e0.x, d);
      d = fmaf(-z[1], e0.y, d);
      d = fmaf(-z[2], e0.z, d);
      d = fmaf(-z[3], e0.w, d);
      d = fmaf(-z[4], e1.x, d);
      d = fmaf(-z[5], e1.y, d);
      d = fmaf(-z[6], e1.z, d);
      d = fmaf(-z[7], e1.w, d);
      if (__any(d < b2)) {              // wave-uniform skip
        const bool lt1 = d < b1;
        const bool lt2 = d < b2;
        i2 = lt1 ? i1 : (lt2 ? ii : i2);
        b2 = __builtin_amdgcn_fmed3f(d, b1, b2);   // == min(max(d,b1),b2)
        i1 = lt1 ? ii : i1;
        b1 = fminf(d, b1);
      }
    }
  }

  float c1[EDIM], c2[EDIM];
  *(float4*)(c1)     = *(const float4*)(CB + (size_t)i1 * EDIM);
  *(float4*)(c1 + 4) = *(const float4*)(CB + (size_t)i1 * EDIM + 4);
  if (b2 - b1 < 1e-3f) {            // near-tie: exact fp64 pair compare
    *(float4*)(c2)     = *(const float4*)(CB + (size_t)i2 * EDIM);
    *(float4*)(c2 + 4) = *(const float4*)(CB + (size_t)i2 * EDIM + 4);
    double d1 = 0.0, d2 = 0.0;
#pragma unroll
    for (int j = 0; j < EDIM; ++j) {
      double f1 = (double)z[j] - (double)c1[j];
      double f2 = (double)z[j] - (double)c2[j];
      d1 += f1 * f1; d2 += f2 * f2;
    }
    if (d2 < d1 || (d2 == d1 && i2 < i1)) {
      i1 = i2;
#pragma unroll
      for (int j = 0; j < EDIM; ++j) c1[j] = c2[j];
    }
  }
  double lsum = 0.0;
#pragma unroll
  for (int j = 0; j < EDIM; ++j) {
    double diff = (double)z[j] - (double)c1[j];
    lsum += diff * diff;
  }

  uint4 pk;
  pk.x = (unsigned)f2bf(fmaxf(c1[0], 0.0f)) | ((unsigned)f2bf(fmaxf(c1[1], 0.0f)) << 16);
  pk.y = (unsigned)f2bf(fmaxf(c1[2], 0.0f)) | ((unsigned)f2bf(fmaxf(c1[3], 0.0f)) << 16);
  pk.z = (unsigned)f2bf(fmaxf(c1[4], 0.0f)) | ((unsigned)f2bf(fmaxf(c1[5], 0.0f)) << 16);
  pk.w = (unsigned)f2bf(fmaxf(c1[6], 0.0f)) | ((unsigned)f2bf(fmaxf(c1[7], 0.0f)) << 16);
  *(uint4*)(ZQb + sv * EDIM) = pk;

#pragma unroll
  for (int off = 32; off > 0; off >>= 1) lsum += __shfl_down(lsum, off);
  __shared__ double lsh[4];
  if ((t & 63) == 0) lsh[t >> 6] = lsum;
  __syncthreads();
  if (t == 0) partial[blockIdx.x] = (float)(lsh[0] + lsh[1] + lsh[2] + lsh[3]);
}

__global__ __launch_bounds__(256) void loss_finalize(
    const float* __restrict__ partial, float* __restrict__ out)
{
  const int t = threadIdx.x;
  double s = 0.0;
  for (int i = t; i < 2048; i += 256) s += (double)partial[i];
#pragma unroll
  for (int off = 32; off > 0; off >>= 1) s += __shfl_down(s, off);
  __shared__ double ls[4];
  if ((t & 63) == 0) ls[t >> 6] = s;
  __syncthreads();
  if (t == 0) {
    double total = ls[0] + ls[1] + ls[2] + ls[3];
    out[0] = (float)(total * (1.0 + (double)BETA) / (double)((size_t)BATCH * HID));
  }
}

} // namespace

extern "C" void kernel_launch(void* const* d_in, const int* in_sizes, int n_in,
                              void* d_out, int out_size, void* d_ws, size_t ws_size,
                              hipStream_t stream)
{
  const float* x   = (const float*)d_in[0];
  const float* cb  = (const float*)d_in[1];
  const float* W0  = (const float*)d_in[2];
  const float* b0  = (const float*)d_in[3];
  const float* g0  = (const float*)d_in[4];
  const float* be0 = (const float*)d_in[5];
  const float* W1  = (const float*)d_in[6];
  const float* b1  = (const float*)d_in[7];
  const float* g1  = (const float*)d_in[8];
  const float* be1 = (const float*)d_in[9];
  const float* W2  = (const float*)d_in[10];
  const float* b2  = (const float*)d_in[11];
  const float* g2  = (const float*)d_in[12];
  const float* be2 = (const float*)d_in[13];
  const float* W3  = (const float*)d_in[14];
  const float* b3  = (const float*)d_in[15];
  const float* g3  = (const float*)d_in[16];
  const float* be3 = (const float*)d_in[17];
  const float* W4  = (const float*)d_in[18];
  const float* b4  = (const float*)d_in[19];
  const float* g4  = (const float*)d_in[20];
  const float* be4 = (const float*)d_in[21];
  const float* W5  = (const float*)d_in[22];
  const float* b5  = (const float*)d_in[23];
  float* out = (float*)d_out;

  char* ws = (char*)d_ws;
  constexpr size_t MB = 1024 * 1024;
  // ws (proven bound 32MB+8KB; max extent exactly 32MB+8KB):
  float* C32 = (float*)ws;                               // [0,16) decoder GEMM out
  float* Q   = (float*)(ws + 16 * MB);                   // [16,32) fp32 acts (encoder)
  unsigned short* Qb  = (unsigned short*)(ws + 16 * MB); // [16,24) bf16 acts (decoder)
  unsigned short* W3H = (unsigned short*)(ws + 24 * MB); // [24,26)
  unsigned short* W4H = (unsigned short*)(ws + 26 * MB); // [26,28)
  unsigned short* W5H = (unsigned short*)(ws + 28 * MB); // [28,32)
  float* partial = (float*)(ws + 32 * MB);               // 8 KB (2048 floats)
  // d_out (32MB) scratch during encoder: P0/P1 partials; then Z over P1.
  float* P0 = (float*)d_out;                             // [0,16)
  float* P1 = (float*)((char*)d_out + 16 * MB);          // [16,32)
  float* Z  = (float*)((char*)d_out + 16 * MB);          // [16,32) after G2-LN (in-place)
  float* QN = (float*)d_out;                             // [0,4KB) after ln_sk G2 (P0 dead)

  dim3 blk(256);
  dim3 gSK(HID / 128, BATCH / 128, 2);  // split-K=2 fp32 GEMMs: 512 blocks
  dim3 gDH(HID / 64, BATCH / 128);      // decoder N=1024: 512 blocks
  dim3 gDO(DIN / 64, BATCH / 128);      // decoder N=2048: 1024 blocks

  // --- encoder (fp32 split-K=2 + fused reduce/bias/LN) ---
  gemm_f32_sk<<<gSK, blk, 0, stream>>>(x, W0, P0, BATCH, HID, DIN);
  ln_sk<true><<<dim3(BATCH), blk, 0, stream>>>(P0, P1, b0, Q, g0, be0);
  gemm_f32_sk<<<gSK, blk, 0, stream>>>(Q, W1, P0, BATCH, HID, HID);
  ln_sk<true><<<dim3(BATCH), blk, 0, stream>>>(P0, P1, b1, Q, g1, be1);
  gemm_f32_sk<<<gSK, blk, 0, stream>>>(Q, W2, P0, BATCH, HID, HID);
  ln_sk<false><<<dim3(BATCH), blk, 0, stream>>>(P0, P1, b2, Z, g2, be2);  // z (in-place)

  // --- decoder weights into [24,32) (Q dead after G2) + qn precompute ---
  conv_w_t<<<dim3(HID / 32, HID / 32), blk, 0, stream>>>(W3, W3H, HID, HID);
  conv_w_t<<<dim3(HID / 32, HID / 32), blk, 0, stream>>>(W4, W4H, HID, HID);
  conv_w_t<<<dim3(DIN / 32, HID / 32), blk, 0, stream>>>(W5, W5H, HID, DIN);
  prep_qn<<<dim3(NEMB / 256), blk, 0, stream>>>(cb, QN);   // P0 dead after G2-LN

  // --- vector quantize: z -> bf16 relu(z_q) in Qb + loss partials ---
  vq_kernel<<<dim3(2048), blk, 0, stream>>>(Z, cb, QN, Qb, partial);

  // --- decoder (bf16 MFMA) ---
  gemm_mfma<<<gDH, blk, 0, stream>>>(Qb, W3H, b3, C32, BATCH, HID, HID);
  ln_act<true><<<dim3(BATCH), blk, 0, stream>>>(C32, Qb, g3, be3);
  gemm_mfma<<<gDH, blk, 0, stream>>>(Qb, W4H, b4, C32, BATCH, HID, HID);
  ln_act<true><<<dim3(BATCH), blk, 0, stream>>>(C32, Qb, g4, be4);
  gemm_mfma<<<gDO, blk, 0, stream>>>(Qb, W5H, b5, out, BATCH, DIN, HID);

  loss_finalize<<<dim3(1), blk, 0, stream>>>(partial, out + (size_t)BATCH * DIN);
}

// Round 17
// 765.329 us; speedup vs baseline: 1.2258x; 1.2258x over previous
//
#include <hip/hip_runtime.h>

namespace {

constexpr int BATCH = 4096;
constexpr int DIN   = 2048;
constexpr int HID   = 1024;
constexpr int NEMB  = 1024;
constexpr int EDIM  = 8;
constexpr float LN_EPS = 1e-5f;
constexpr float BETA   = 0.001f;

typedef __attribute__((ext_vector_type(8))) short bf16x8;
typedef __attribute__((ext_vector_type(4))) float f32x4;
typedef __attribute__((ext_vector_type(2))) float f32x2;

__device__ inline unsigned short f2bf(float f) {
  unsigned int x = __float_as_uint(f);
  x += 0x7FFFu + ((x >> 16) & 1u);      // RNE
  return (unsigned short)(x >> 16);
}
__device__ inline void gl16(const void* g, void* l) {
  __builtin_amdgcn_global_load_lds(
      (const __attribute__((address_space(1))) unsigned int*)g,
      (__attribute__((address_space(3))) unsigned int*)l, 16, 0, 0);
}

// ---------------- GEMM fp32 split-K=2 (encoder) — R12-proven config -------
// BK=16 single-buffer + prefetch + Bs swizzle. Five restructure attempts
// (R14 pk-fma, R15 BK=32, R16 dbuf) all null/regressed: this shape sits in
// a narrow VGPR sweet spot (104) at 68% of its LDS-pipe floor. Do not touch.
__global__ __launch_bounds__(256) void gemm_f32_sk(
    const float* __restrict__ A, const float* __restrict__ B,
    float* __restrict__ P, int M, int N, int K)
{
  constexpr int BM = 128, BN = 128, BK = 16;
  __shared__ float As[BK][BM + 4];       // 8448 B
  __shared__ float Bsf[16 * 132];        // 8448 B, j-stride 132
  const int t  = threadIdx.x;
  const int tx = t & 15, ty = t >> 4;
  const int bm = blockIdx.y * BM, bn = blockIdx.x * BN;
  const int Kh = K >> 1, kbeg = blockIdx.z * Kh;
  const int NT = Kh / BK;
  float* Pz = P + (size_t)blockIdx.z * M * N;

  const int a_m = t >> 1, a_k = (t & 1) << 3;
  const int b_k = t >> 4;

  const float* Ap = A + (size_t)(bm + a_m) * K + kbeg + a_k;
  const float* Bp = B + (size_t)(kbeg + b_k) * N + (bn + tx * 8);

  float4 av0, av1, bv0, bv1;
  auto GLOAD = [&](int tk) {
    const int k0 = tk * BK;
    av0 = *(const float4*)(Ap + k0);
    av1 = *(const float4*)(Ap + k0 + 4);
    bv0 = *(const float4*)(Bp + (size_t)k0 * N);
    bv1 = *(const float4*)(Bp + (size_t)k0 * N + 4);
  };
  auto SWRITE = [&]() {
    As[a_k + 0][a_m] = av0.x;
    As[a_k + 1][a_m] = av0.y;
    As[a_k + 2][a_m] = av0.z;
    As[a_k + 3][a_m] = av0.w;
    As[a_k + 4][a_m] = av1.x;
    As[a_k + 5][a_m] = av1.y;
    As[a_k + 6][a_m] = av1.z;
    As[a_k + 7][a_m] = av1.w;
    float* Bq = &Bsf[tx * 132 + b_k * 8];
    *(float4*)(Bq)     = bv0;
    *(float4*)(Bq + 4) = bv1;
  };

  float acc[8][8] = {};

  GLOAD(0);
  for (int tk = 0; tk < NT; ++tk) {
    __syncthreads();                 // all waves done reading previous tile
    SWRITE();                        // vmcnt wait lands here (loads long issued)
    __syncthreads();                 // tile visible
    if (tk + 1 < NT) GLOAD(tk + 1);  // prefetch: latency hides under compute

    float part[8][8] = {};
#pragma unroll
    for (int k = 0; k < BK; ++k) {
      float a[8], b[8];
      *(float4*)(a)     = *(const float4*)&As[k][ty * 8];
      *(float4*)(a + 4) = *(const float4*)&As[k][ty * 8 + 4];
      *(float4*)(b)     = *(const float4*)&Bsf[tx * 132 + k * 8];
      *(float4*)(b + 4) = *(const float4*)&Bsf[tx * 132 + k * 8 + 4];
#pragma unroll
      for (int i = 0; i < 8; ++i)
#pragma unroll
        for (int j = 0; j < 8; ++j)
          part[i][j] = fmaf(a[i], b[j], part[i][j]);
    }
#pragma unroll
    for (int i = 0; i < 8; ++i)
#pragma unroll
      for (int j = 0; j < 8; ++j)
        acc[i][j] += part[i][j];
  }

#pragma unroll
  for (int i = 0; i < 8; ++i) {
    float* Pr = Pz + (size_t)(bm + ty * 8 + i) * N + bn + tx * 8;
    *(float4*)(Pr)     = *(float4*)&acc[i][0];
    *(float4*)(Pr + 4) = *(float4*)&acc[i][4];
  }
}

// ---------------- fused reduce + bias + LayerNorm (+ReLU), f32 out --------
template<bool RELU>
__global__ __launch_bounds__(256) void ln_sk(
    const float* __restrict__ P0, const float* __restrict__ P1,
    const float* __restrict__ bias, float* __restrict__ Y,
    const float* __restrict__ g, const float* __restrict__ be)
{
  const int t = threadIdx.x;
  const size_t base = (size_t)blockIdx.x * HID + t * 4;
  float4 p0 = *(const float4*)(P0 + base);
  float4 p1 = *(const float4*)(P1 + base);
  float4 bb = *(const float4*)(bias + t * 4);
  float4 v;
  v.x = (p0.x + p1.x) + bb.x;
  v.y = (p0.y + p1.y) + bb.y;
  v.z = (p0.z + p1.z) + bb.z;
  v.w = (p0.w + p1.w) + bb.w;
  float s = v.x + v.y + v.z + v.w;
  float q = v.x * v.x + v.y * v.y + v.z * v.z + v.w * v.w;
#pragma unroll
  for (int off = 32; off > 0; off >>= 1) {
    s += __shfl_down(s, off);
    q += __shfl_down(q, off);
  }
  __shared__ float ls[4], lq[4];
  if ((t & 63) == 0) { ls[t >> 6] = s; lq[t >> 6] = q; }
  __syncthreads();
  s = ls[0] + ls[1] + ls[2] + ls[3];
  q = lq[0] + lq[1] + lq[2] + lq[3];
  const float mean = s * (1.0f / HID);
  const float var  = q * (1.0f / HID) - mean * mean;
  const float rstd = rsqrtf(var + LN_EPS);
  float4 gv = *(const float4*)(g + t * 4);
  float4 bv = *(const float4*)(be + t * 4);
  float4 o;
  o.x = (v.x - mean) * rstd * gv.x + bv.x;
  o.y = (v.y - mean) * rstd * gv.y + bv.y;
  o.z = (v.z - mean) * rstd * gv.z + bv.z;
  o.w = (v.w - mean) * rstd * gv.w + bv.w;
  if (RELU) {
    o.x = fmaxf(o.x, 0.0f); o.y = fmaxf(o.y, 0.0f);
    o.z = fmaxf(o.z, 0.0f); o.w = fmaxf(o.w, 0.0f);
  }
  *(float4*)(Y + base) = o;
}

// ---------------- GEMM bf16 MFMA (decoder) — R6-proven --------------------
__global__ __launch_bounds__(256) void gemm_mfma(
    const unsigned short* __restrict__ Ah, const unsigned short* __restrict__ Bh,
    const float* __restrict__ bias, float* __restrict__ C,
    int M, int N, int K)
{
  constexpr int BM = 128, BN = 64, BK = 64;
  __shared__ unsigned short lds[(BM + BN) * BK];        // 24 KB
  const int t = threadIdx.x, l = t & 63, w = t >> 6;
  const int wr = w >> 1, wc = w & 1;
  const int m0 = blockIdx.y * BM, n0 = blockIdx.x * BN;
  const int NT = K / BK;

  const int AHo = 0, BHo = BM * BK * 2;

  const int srow = t >> 3, scol = t & 7;
  size_t aoff[4]; int adst[4];
#pragma unroll
  for (int i = 0; i < 4; ++i) {
    int r = srow + 32 * i;
    aoff[i] = (size_t)(m0 + r) * K + ((scol ^ (r & 7)) << 3);
    adst[i] = r * 128 + scol * 16;
  }
  size_t boff[2]; int bdst[2];
#pragma unroll
  for (int i = 0; i < 2; ++i) {
    int r = srow + 32 * i;
    boff[i] = (size_t)(n0 + r) * K + ((scol ^ (r & 7)) << 3);
    bdst[i] = r * 128 + scol * 16;
  }
  char* lc = (char*)lds;

  auto GLOAD = [&](int tk) {
    const size_t k0 = (size_t)tk * BK;
#pragma unroll
    for (int i = 0; i < 4; ++i) gl16(Ah + aoff[i] + k0, lc + AHo + adst[i]);
#pragma unroll
    for (int i = 0; i < 2; ++i) gl16(Bh + boff[i] + k0, lc + BHo + bdst[i]);
  };

  f32x4 acc[4][2];
#pragma unroll
  for (int i = 0; i < 4; ++i)
#pragma unroll
    for (int j = 0; j < 2; ++j) acc[i][j] = 0.0f;

  const int l15 = l & 15, kb0 = l >> 4;
  const int swz = (l15 & 7) << 4;
  int arow[4], brow[2];
#pragma unroll
  for (int fm = 0; fm < 4; ++fm) arow[fm] = (wr * 64 + fm * 16 + l15) * 128;
#pragma unroll
  for (int fn = 0; fn < 2; ++fn) brow[fn] = (wc * 32 + fn * 16 + l15) * 128;

  GLOAD(0);
  for (int tk = 0; tk < NT; ++tk) {
    __syncthreads();
    const char* p = (const char*)lds;
#pragma unroll
    for (int kh = 0; kh < 2; ++kh) {
      const int kby = (kh * 64 + kb0 * 16) ^ swz;
      bf16x8 af[4], bf2[2];
#pragma unroll
      for (int fm = 0; fm < 4; ++fm)
        af[fm] = *(const bf16x8*)(p + AHo + arow[fm] + kby);
#pragma unroll
      for (int fn = 0; fn < 2; ++fn)
        bf2[fn] = *(const bf16x8*)(p + BHo + brow[fn] + kby);
#pragma unroll
      for (int fm = 0; fm < 4; ++fm)
#pragma unroll
        for (int fn = 0; fn < 2; ++fn)
          acc[fm][fn] = __builtin_amdgcn_mfma_f32_16x16x32_bf16(
              af[fm], bf2[fn], acc[fm][fn], 0, 0, 0);
    }
    __syncthreads();
    if (tk + 1 < NT) GLOAD(tk + 1);
  }

  const int rb = (l >> 4) * 4;
#pragma unroll
  for (int fn = 0; fn < 2; ++fn) {
    const int n = n0 + wc * 32 + fn * 16 + l15;
    const float bv = bias[n];
#pragma unroll
    for (int fm = 0; fm < 4; ++fm) {
      const int m = m0 + wr * 64 + fm * 16 + rb;
      float* Cp = C + (size_t)m * N + n;
#pragma unroll
      for (int ri = 0; ri < 4; ++ri)
        Cp[(size_t)ri * N] = acc[fm][fn][ri] + bv;
    }
  }
}

// ---------------- weight convert + transpose: Wt[N][K] bf16 ---------------
__global__ __launch_bounds__(256) void conv_w_t(
    const float* __restrict__ W, unsigned short* __restrict__ Wt, int K, int N)
{
  __shared__ float tile[32][33];
  const int tx = threadIdx.x & 31, ty = threadIdx.x >> 5;
  const int n0 = blockIdx.x * 32, k0 = blockIdx.y * 32;
#pragma unroll
  for (int r = ty; r < 32; r += 8)
    tile[r][tx] = W[(size_t)(k0 + r) * N + n0 + tx];
  __syncthreads();
#pragma unroll
  for (int r = ty; r < 32; r += 8)
    Wt[(size_t)(n0 + r) * K + k0 + tx] = f2bf(tile[tx][r]);
}

// ---------------- LayerNorm (+ReLU), f32 in, bf16 out (decoder) -----------
template<bool RELU>
__global__ __launch_bounds__(256) void ln_act(
    const float* __restrict__ X, unsigned short* __restrict__ Y,
    const float* __restrict__ g, const float* __restrict__ be)
{
  const int t = threadIdx.x;
  const size_t base = (size_t)blockIdx.x * HID + t * 4;
  float4 v = *(const float4*)(X + base);
  float s = v.x + v.y + v.z + v.w;
  float q = v.x * v.x + v.y * v.y + v.z * v.z + v.w * v.w;
#pragma unroll
  for (int off = 32; off > 0; off >>= 1) {
    s += __shfl_down(s, off);
    q += __shfl_down(q, off);
  }
  __shared__ float ls[4], lq[4];
  if ((t & 63) == 0) { ls[t >> 6] = s; lq[t >> 6] = q; }
  __syncthreads();
  s = ls[0] + ls[1] + ls[2] + ls[3];
  q = lq[0] + lq[1] + lq[2] + lq[3];
  const float mean = s * (1.0f / HID);
  const float var  = q * (1.0f / HID) - mean * mean;
  const float rstd = rsqrtf(var + LN_EPS);
  float4 gv = *(const float4*)(g + t * 4);
  float4 bv = *(const float4*)(be + t * 4);
  float4 o;
  o.x = (v.x - mean) * rstd * gv.x + bv.x;
  o.y = (v.y - mean) * rstd * gv.y + bv.y;
  o.z = (v.z - mean) * rstd * gv.z + bv.z;
  o.w = (v.w - mean) * rstd * gv.w + bv.w;
  if (RELU) {
    o.x = fmaxf(o.x, 0.0f); o.y = fmaxf(o.y, 0.0f);
    o.z = fmaxf(o.z, 0.0f); o.w = fmaxf(o.w, 0.0f);
  }
  ushort4 u = { f2bf(o.x), f2bf(o.y), f2bf(o.z), f2bf(o.w) };
  *(ushort4*)(Y + base) = u;
}

// ---------------- qn precompute: qn[i] = 0.5*|e_i|^2 ----------------------
__global__ __launch_bounds__(256) void prep_qn(
    const float* __restrict__ CB, float* __restrict__ QN)
{
  const int i = blockIdx.x * 256 + threadIdx.x;
  const float* e = CB + (size_t)i * EDIM;
  float s = 0.0f;
#pragma unroll
  for (int j = 0; j < EDIM; ++j) s += e[j] * e[j];
  QN[i] = 0.5f * s;
}

// ---------------- VQ v9: packed-FMA scoring (v_pk_fma_f32) ----------------
// Per entry: acc={qn,0}; 4 pk_fma with negated-z pairs; d = acc.x+acc.y.
// 5-6 VALU vs 8 scalar FMA. Within-entry sum regrouped (pairwise halves) —
// score noise ~1e-7; selection protected by the fp64 pairwise fixup at
// gap<1e-3. Scan order over entries, tracking, and fixup unchanged from v8.
__global__ __launch_bounds__(256) void vq_kernel(
    const float* __restrict__ Z, const float* __restrict__ CB,
    const float* __restrict__ QN,
    unsigned short* __restrict__ ZQb, float* __restrict__ partial)
{
  const int t = threadIdx.x;
  const size_t sv = (size_t)blockIdx.x * 256 + t;
  float z[EDIM];
  *(float4*)(z)     = *(const float4*)(Z + sv * EDIM);
  *(float4*)(z + 4) = *(const float4*)(Z + sv * EDIM + 4);
  f32x2 nz[4];
#pragma unroll
  for (int j = 0; j < 4; ++j) nz[j] = f32x2{-z[2 * j], -z[2 * j + 1]};

  float b1 = 1e30f, b2 = 1e30f;
  int   i1 = 0, i2 = 0;

  for (int i = 0; i < NEMB; i += 4) {
    const float4 qv = *(const float4*)(QN + i);          // uniform -> s_load
#pragma unroll
    for (int u = 0; u < 4; ++u) {
      const float4 e0 = *(const float4*)(CB + (size_t)(i + u) * EDIM);
      const float4 e1 = *(const float4*)(CB + (size_t)(i + u) * EDIM + 4);
      const float q = (u == 0) ? qv.x : (u == 1) ? qv.y : (u == 2) ? qv.z : qv.w;
      const int ii = i + u;
      f32x2 acc = {q, 0.0f};
      acc = __builtin_elementwise_fma(nz[0], f32x2{e0.x, e0.y}, acc);
      acc = __builtin_elementwise_fma(nz[1], f32x2{e0.z, e0.w}, acc);
      acc = __builtin_elementwise_fma(nz[2], f32x2{e1.x, e1.y}, acc);
      acc = __builtin_elementwise_fma(nz[3], f32x2{e1.z, e1.w}, acc);
      const float d = acc.x + acc.y;
      if (__any(d < b2)) {              // wave-uniform skip
        const bool lt1 = d < b1;
        const bool lt2 = d < b2;
        i2 = lt1 ? i1 : (lt2 ? ii : i2);
        b2 = __builtin_amdgcn_fmed3f(d, b1, b2);   // == min(max(d,b1),b2)
        i1 = lt1 ? ii : i1;
        b1 = fminf(d, b1);
      }
    }
  }

  float c1[EDIM], c2[EDIM];
  *(float4*)(c1)     = *(const float4*)(CB + (size_t)i1 * EDIM);
  *(float4*)(c1 + 4) = *(const float4*)(CB + (size_t)i1 * EDIM + 4);
  if (b2 - b1 < 1e-3f) {            // near-tie: exact fp64 pair compare
    *(float4*)(c2)     = *(const float4*)(CB + (size_t)i2 * EDIM);
    *(float4*)(c2 + 4) = *(const float4*)(CB + (size_t)i2 * EDIM + 4);
    double d1 = 0.0, d2 = 0.0;
#pragma unroll
    for (int j = 0; j < EDIM; ++j) {
      double f1 = (double)z[j] - (double)c1[j];
      double f2 = (double)z[j] - (double)c2[j];
      d1 += f1 * f1; d2 += f2 * f2;
    }
    if (d2 < d1 || (d2 == d1 && i2 < i1)) {
      i1 = i2;
#pragma unroll
      for (int j = 0; j < EDIM; ++j) c1[j] = c2[j];
    }
  }
  double lsum = 0.0;
#pragma unroll
  for (int j = 0; j < EDIM; ++j) {
    double diff = (double)z[j] - (double)c1[j];
    lsum += diff * diff;
  }

  uint4 pk;
  pk.x = (unsigned)f2bf(fmaxf(c1[0], 0.0f)) | ((unsigned)f2bf(fmaxf(c1[1], 0.0f)) << 16);
  pk.y = (unsigned)f2bf(fmaxf(c1[2], 0.0f)) | ((unsigned)f2bf(fmaxf(c1[3], 0.0f)) << 16);
  pk.z = (unsigned)f2bf(fmaxf(c1[4], 0.0f)) | ((unsigned)f2bf(fmaxf(c1[5], 0.0f)) << 16);
  pk.w = (unsigned)f2bf(fmaxf(c1[6], 0.0f)) | ((unsigned)f2bf(fmaxf(c1[7], 0.0f)) << 16);
  *(uint4*)(ZQb + sv * EDIM) = pk;

#pragma unroll
  for (int off = 32; off > 0; off >>= 1) lsum += __shfl_down(lsum, off);
  __shared__ double lsh[4];
  if ((t & 63) == 0) lsh[t >> 6] = lsum;
  __syncthreads();
  if (t == 0) partial[blockIdx.x] = (float)(lsh[0] + lsh[1] + lsh[2] + lsh[3]);
}

__global__ __launch_bounds__(256) void loss_finalize(
    const float* __restrict__ partial, float* __restrict__ out)
{
  const int t = threadIdx.x;
  double s = 0.0;
  for (int i = t; i < 2048; i += 256) s += (double)partial[i];
#pragma unroll
  for (int off = 32; off > 0; off >>= 1) s += __shfl_down(s, off);
  __shared__ double ls[4];
  if ((t & 63) == 0) ls[t >> 6] = s;
  __syncthreads();
  if (t == 0) {
    double total = ls[0] + ls[1] + ls[2] + ls[3];
    out[0] = (float)(total * (1.0 + (double)BETA) / (double)((size_t)BATCH * HID));
  }
}

} // namespace

extern "C" void kernel_launch(void* const* d_in, const int* in_sizes, int n_in,
                              void* d_out, int out_size, void* d_ws, size_t ws_size,
                              hipStream_t stream)
{
  const float* x   = (const float*)d_in[0];
  const float* cb  = (const float*)d_in[1];
  const float* W0  = (const float*)d_in[2];
  const float* b0  = (const float*)d_in[3];
  const float* g0  = (const float*)d_in[4];
  const float* be0 = (const float*)d_in[5];
  const float* W1  = (const float*)d_in[6];
  const float* b1  = (const float*)d_in[7];
  const float* g1  = (const float*)d_in[8];
  const float* be1 = (const float*)d_in[9];
  const float* W2  = (const float*)d_in[10];
  const float* b2  = (const float*)d_in[11];
  const float* g2  = (const float*)d_in[12];
  const float* be2 = (const float*)d_in[13];
  const float* W3  = (const float*)d_in[14];
  const float* b3  = (const float*)d_in[15];
  const float* g3  = (const float*)d_in[16];
  const float* be3 = (const float*)d_in[17];
  const float* W4  = (const float*)d_in[18];
  const float* b4  = (const float*)d_in[19];
  const float* g4  = (const float*)d_in[20];
  const float* be4 = (const float*)d_in[21];
  const float* W5  = (const float*)d_in[22];
  const float* b5  = (const float*)d_in[23];
  float* out = (float*)d_out;

  char* ws = (char*)d_ws;
  constexpr size_t MB = 1024 * 1024;
  // ws (proven bound 32MB+8KB; max extent exactly 32MB+8KB):
  float* C32 = (float*)ws;                               // [0,16) decoder GEMM out
  float* Q   = (float*)(ws + 16 * MB);                   // [16,32) fp32 acts (encoder)
  unsigned short* Qb  = (unsigned short*)(ws + 16 * MB); // [16,24) bf16 acts (decoder)
  unsigned short* W3H = (unsigned short*)(ws + 24 * MB); // [24,26)
  unsigned short* W4H = (unsigned short*)(ws + 26 * MB); // [26,28)
  unsigned short* W5H = (unsigned short*)(ws + 28 * MB); // [28,32)
  float* partial = (float*)(ws + 32 * MB);               // 8 KB (2048 floats)
  // d_out (32MB) scratch during encoder: P0/P1 partials; then Z over P1.
  float* P0 = (float*)d_out;                             // [0,16)
  float* P1 = (float*)((char*)d_out + 16 * MB);          // [16,32)
  float* Z  = (float*)((char*)d_out + 16 * MB);          // [16,32) after G2-LN (in-place)
  float* QN = (float*)d_out;                             // [0,4KB) after ln_sk G2 (P0 dead)

  dim3 blk(256);
  dim3 gSK(HID / 128, BATCH / 128, 2);  // split-K=2 fp32 GEMMs: 512 blocks
  dim3 gDH(HID / 64, BATCH / 128);      // decoder N=1024: 512 blocks
  dim3 gDO(DIN / 64, BATCH / 128);      // decoder N=2048: 1024 blocks

  // --- encoder (fp32 split-K=2 + fused reduce/bias/LN) ---
  gemm_f32_sk<<<gSK, blk, 0, stream>>>(x, W0, P0, BATCH, HID, DIN);
  ln_sk<true><<<dim3(BATCH), blk, 0, stream>>>(P0, P1, b0, Q, g0, be0);
  gemm_f32_sk<<<gSK, blk, 0, stream>>>(Q, W1, P0, BATCH, HID, HID);
  ln_sk<true><<<dim3(BATCH), blk, 0, stream>>>(P0, P1, b1, Q, g1, be1);
  gemm_f32_sk<<<gSK, blk, 0, stream>>>(Q, W2, P0, BATCH, HID, HID);
  ln_sk<false><<<dim3(BATCH), blk, 0, stream>>>(P0, P1, b2, Z, g2, be2);  // z (in-place)

  // --- decoder weights into [24,32) (Q dead after G2) + qn precompute ---
  conv_w_t<<<dim3(HID / 32, HID / 32), blk, 0, stream>>>(W3, W3H, HID, HID);
  conv_w_t<<<dim3(HID / 32, HID / 32), blk, 0, stream>>>(W4, W4H, HID, HID);
  conv_w_t<<<dim3(DIN / 32, HID / 32), blk, 0, stream>>>(W5, W5H, HID, DIN);
  prep_qn<<<dim3(NEMB / 256), blk, 0, stream>>>(cb, QN);   // P0 dead after G2-LN

  // --- vector quantize: z -> bf16 relu(z_q) in Qb + loss partials ---
  vq_kernel<<<dim3(2048), blk, 0, stream>>>(Z, cb, QN, Qb, partial);

  // --- decoder (bf16 MFMA) ---
  gemm_mfma<<<gDH, blk, 0, stream>>>(Qb, W3H, b3, C32, BATCH, HID, HID);
  ln_act<true><<<dim3(BATCH), blk, 0, stream>>>(C32, Qb, g3, be3);
  gemm_mfma<<<gDH, blk, 0, stream>>>(Qb, W4H, b4, C32, BATCH, HID, HID);
  ln_act<true><<<dim3(BATCH), blk, 0, stream>>>(C32, Qb, g4, be4);
  gemm_mfma<<<gDO, blk, 0, stream>>>(Qb, W5H, b5, out, BATCH, DIN, HID);

  loss_finalize<<<dim3(1), blk, 0, stream>>>(partial, out + (size_t)BATCH * DIN);
}